// Round 1
// baseline (54.192 us; speedup 1.0000x reference)
//
#include <hip/hip_runtime.h>

// FFD cubic B-spline flow generation.
// mesh: [4][3][23][27][23] f32, out: [4][3][160][192][160] f32.
// spacing = 8 on every axis -> d = (i&7)/8 (8 distinct weight rows), pivot = i>>3.

#define SPX 160
#define SPY 192
#define SPZ 160
#define CPX 23
#define CPY 27
#define CPZ 23

// padded LDS row length for z (168 % 32 == 8 -> 2-way max conflict on b128 reads)
#define ZP 168

__global__ __launch_bounds__(256) void ffd_kernel(const float* __restrict__ mesh,
                                                  float* __restrict__ out) {
    const int yb  = blockIdx.x;   // 0..23  (y blocks of 8)
    const int xb  = blockIdx.y;   // 0..19  (x blocks of 8)
    const int bc  = blockIdx.z;   // 0..11  (b*3 + c)
    const int tid = threadIdx.x;

    __shared__ float wlds[8][4];
    __shared__ float m_lds[4][4][24];          // [a][b2][cz], cz padded 23->24
    __shared__ __align__(16) float tA[4][4][ZP];  // z-contracted
    __shared__ __align__(16) float tB[4][8][ZP];  // z+y-contracted

    // cubic B-spline weights for the 8 fractional offsets
    if (tid < 32) {
        int j = tid >> 2, a = tid & 3;
        float d  = (float)j * 0.125f;
        float d2 = d * d, d3 = d2 * d;
        float w;
        if (a == 0)      { float e = 1.0f - d; w = e * e * e * (1.0f / 6.0f); }
        else if (a == 1) { w = 0.5f * d3 - d2 + (2.0f / 3.0f); }
        else if (a == 2) { w = -0.5f * d3 + 0.5f * d2 + 0.5f * d + (1.0f / 6.0f); }
        else             { w = d3 * (1.0f / 6.0f); }
        wlds[j][a] = w;
    }

    // stage 0: mesh sub-block [xb..xb+3][yb..yb+3][0..22] -> LDS
    const float* mch = mesh + (size_t)bc * (CPX * CPY * CPZ);
    for (int i = tid; i < 4 * 4 * CPZ; i += 256) {
        int cz = i % CPZ;
        int r  = i / CPZ;
        int b2 = r & 3;
        int a  = r >> 2;
        m_lds[a][b2][cz] = mch[(xb + a) * (CPY * CPZ) + (yb + b2) * CPZ + cz];
    }
    __syncthreads();

    // stage 1: contract z. tA[a][b2][z] = sum_c2 w[z&7][c2] * m[a][b2][(z>>3)+c2]
    for (int i = tid; i < 4 * 4 * SPZ; i += 256) {
        int z  = i % SPZ;
        int r  = i / SPZ;
        int b2 = r & 3;
        int a  = r >> 2;
        int piv = z >> 3, j = z & 7;
        float acc = wlds[j][0] * m_lds[a][b2][piv]
                  + wlds[j][1] * m_lds[a][b2][piv + 1]
                  + wlds[j][2] * m_lds[a][b2][piv + 2]
                  + wlds[j][3] * m_lds[a][b2][piv + 3];
        tA[a][b2][z] = acc;
    }
    __syncthreads();

    // stage 2: contract y. tB[a][y8][z] = sum_b2 w[y8][b2] * tA[a][b2][z]
    for (int i = tid; i < 4 * 8 * SPZ; i += 256) {
        int z  = i % SPZ;
        int r  = i / SPZ;
        int y8 = r & 7;
        int a  = r >> 3;
        float acc = wlds[y8][0] * tA[a][0][z]
                  + wlds[y8][1] * tA[a][1][z]
                  + wlds[y8][2] * tA[a][2][z]
                  + wlds[y8][3] * tA[a][3][z];
        tB[a][y8][z] = acc;
    }
    __syncthreads();

    // stage 3: contract x, write 8x8x160 outputs.
    // 4 lanes per (x8,y8) row; each lane emits 10 float4s interleaved so a
    // 4-lane group covers a 64B-aligned contiguous chunk per iteration.
    const int g  = tid >> 2;   // 0..63
    const int zt = tid & 3;
    const int x8 = g >> 3;
    const int y8 = g & 7;
    const float w0 = wlds[x8][0], w1 = wlds[x8][1], w2 = wlds[x8][2], w3 = wlds[x8][3];

    float* orow = out + ((size_t)bc * SPX * SPY
                       + (size_t)(xb * 8 + x8) * SPY
                       + (size_t)(yb * 8 + y8)) * SPZ;
    #pragma unroll
    for (int k = 0; k < 10; ++k) {
        int z = (zt + 4 * k) * 4;
        float4 v0 = *(const float4*)&tB[0][y8][z];
        float4 v1 = *(const float4*)&tB[1][y8][z];
        float4 v2 = *(const float4*)&tB[2][y8][z];
        float4 v3 = *(const float4*)&tB[3][y8][z];
        float4 o;
        o.x = w0 * v0.x + w1 * v1.x + w2 * v2.x + w3 * v3.x;
        o.y = w0 * v0.y + w1 * v1.y + w2 * v2.y + w3 * v3.y;
        o.z = w0 * v0.z + w1 * v1.z + w2 * v2.z + w3 * v3.z;
        o.w = w0 * v0.w + w1 * v1.w + w2 * v2.w + w3 * v3.w;
        *(float4*)&orow[z] = o;
    }
}

extern "C" void kernel_launch(void* const* d_in, const int* in_sizes, int n_in,
                              void* d_out, int out_size, void* d_ws, size_t ws_size,
                              hipStream_t stream) {
    const float* mesh = (const float*)d_in[0];
    float* out = (float*)d_out;
    dim3 grid(SPY / 8, SPX / 8, 4 * 3);   // (24, 20, 12)
    ffd_kernel<<<grid, 256, 0, stream>>>(mesh, out);
}

// Round 2
// 46.289 us; speedup vs baseline: 1.1707x; 1.1707x over previous
//
#include <hip/hip_runtime.h>

// FFD cubic B-spline flow generation, separable, contraction order x -> y -> z.
// mesh: [4][3][23][27][23] f32, out: [4][3][160][192][160] f32, spacing 8 all axes.
// d = (i&7)/8 (8 distinct weight rows shared by all axes), pivot = i>>3.

#define SPX 160
#define SPY 192
#define SPZ 160
#define CPX 23
#define CPY 27
#define CPZ 23
#define CZP 25   // padded LDS row stride (odd, coprime with 32 banks)

__global__ __launch_bounds__(256, 8) void ffd_kernel(const float* __restrict__ mesh,
                                                     float* __restrict__ out) {
    const int yb  = blockIdx.x;   // 0..23  (y blocks of 8)
    const int xb  = blockIdx.y;   // 0..19  (x blocks of 8)
    const int bc  = blockIdx.z;   // 0..11  (b*3 + c)
    const int tid = threadIdx.x;

    __shared__ float wlds[8][4];
    __shared__ float tX[8][4][CZP];    // x-contracted:   [x8][b2][cz]
    __shared__ float tXY[8][8][CZP];   // x+y-contracted: [x8][y8][cz]

    // weight table -> LDS (for stages A/B which index it dynamically)
    if (tid < 32) {
        int j = tid >> 2, a = tid & 3;
        float d  = (float)j * 0.125f;
        float d2 = d * d, d3 = d2 * d;
        float w;
        if (a == 0)      { float e = 1.0f - d; w = e * e * e * (1.0f / 6.0f); }
        else if (a == 1) { w = 0.5f * d3 - d2 + (2.0f / 3.0f); }
        else if (a == 2) { w = -0.5f * d3 + 0.5f * d2 + 0.5f * d + (1.0f / 6.0f); }
        else             { w = d3 * (1.0f / 6.0f); }
        wlds[j][a] = w;
    }
    __syncthreads();

    // stage A: contract x directly from global (mesh is L2-resident).
    // tX[x8][b2][cz] = sum_a wlds[x8][a] * mesh[bc][xb+a][yb+b2][cz]
    const float* mch = mesh + (size_t)bc * (CPX * CPY * CPZ);
    for (int i = tid; i < 8 * 4 * CPZ; i += 256) {   // 736 outputs
        int cz = i % CPZ;
        int r  = i / CPZ;
        int b2 = r & 3;
        int x8 = r >> 2;
        const float* mp = mch + (size_t)xb * (CPY * CPZ) + (yb + b2) * CPZ + cz;
        float acc = wlds[x8][0] * mp[0]
                  + wlds[x8][1] * mp[CPY * CPZ]
                  + wlds[x8][2] * mp[2 * CPY * CPZ]
                  + wlds[x8][3] * mp[3 * CPY * CPZ];
        tX[x8][b2][cz] = acc;
    }
    __syncthreads();

    // stage B: contract y.
    // tXY[x8][y8][cz] = sum_b2 wlds[y8][b2] * tX[x8][b2][cz]
    for (int i = tid; i < 8 * 8 * CPZ; i += 256) {   // 1472 outputs
        int cz = i % CPZ;
        int r  = i / CPZ;
        int y8 = r & 7;
        int x8 = r >> 3;
        float acc = wlds[y8][0] * tX[x8][0][cz]
                  + wlds[y8][1] * tX[x8][1][cz]
                  + wlds[y8][2] * tX[x8][2][cz]
                  + wlds[y8][3] * tX[x8][3][cz];
        tXY[x8][y8][cz] = acc;
    }
    __syncthreads();

    // per-thread full weight table in registers (static indexing only) for stage C
    float W[8][4];
    #pragma unroll
    for (int j = 0; j < 8; ++j) {
        float d  = (float)j * 0.125f;
        float d2 = d * d, d3 = d2 * d;
        float e  = 1.0f - d;
        W[j][0] = e * e * e * (1.0f / 6.0f);
        W[j][1] = 0.5f * d3 - d2 + (2.0f / 3.0f);
        W[j][2] = -0.5f * d3 + 0.5f * d2 + 0.5f * d + (1.0f / 6.0f);
        W[j][3] = d3 * (1.0f / 6.0f);
    }

    // stage C: expand z and store.
    // out[x8][y8][8q+e] = sum_c W[e][c] * tXY[x8][y8][q+c]
    // 4 lanes per (x8,y8) row; lane zt handles q = 4k+zt -> each group-iteration
    // writes a contiguous, 128B-aligned 128B chunk.
    const int g  = tid >> 2;   // 0..63
    const int zt = tid & 3;
    const int x8 = g >> 3;
    const int y8 = g & 7;
    const float* trow = &tXY[x8][y8][0];
    float* orow = out + ((size_t)bc * SPX * SPY
                       + (size_t)(xb * 8 + x8) * SPY
                       + (size_t)(yb * 8 + y8)) * SPZ;
    #pragma unroll
    for (int k = 0; k < 5; ++k) {
        int q = 4 * k + zt;          // 0..19
        float m0 = trow[q];
        float m1 = trow[q + 1];
        float m2 = trow[q + 2];
        float m3 = trow[q + 3];
        float4 o0, o1;
        o0.x = W[0][0] * m0 + W[0][1] * m1 + W[0][2] * m2 + W[0][3] * m3;
        o0.y = W[1][0] * m0 + W[1][1] * m1 + W[1][2] * m2 + W[1][3] * m3;
        o0.z = W[2][0] * m0 + W[2][1] * m1 + W[2][2] * m2 + W[2][3] * m3;
        o0.w = W[3][0] * m0 + W[3][1] * m1 + W[3][2] * m2 + W[3][3] * m3;
        o1.x = W[4][0] * m0 + W[4][1] * m1 + W[4][2] * m2 + W[4][3] * m3;
        o1.y = W[5][0] * m0 + W[5][1] * m1 + W[5][2] * m2 + W[5][3] * m3;
        o1.z = W[6][0] * m0 + W[6][1] * m1 + W[6][2] * m2 + W[6][3] * m3;
        o1.w = W[7][0] * m0 + W[7][1] * m1 + W[7][2] * m2 + W[7][3] * m3;
        *(float4*)&orow[8 * q]     = o0;
        *(float4*)&orow[8 * q + 4] = o1;
    }
}

extern "C" void kernel_launch(void* const* d_in, const int* in_sizes, int n_in,
                              void* d_out, int out_size, void* d_ws, size_t ws_size,
                              hipStream_t stream) {
    const float* mesh = (const float*)d_in[0];
    float* out = (float*)d_out;
    dim3 grid(SPY / 8, SPX / 8, 4 * 3);   // (24, 20, 12)
    ffd_kernel<<<grid, 256, 0, stream>>>(mesh, out);
}

// Round 3
// 42.587 us; speedup vs baseline: 1.2725x; 1.0869x over previous
//
#include <hip/hip_runtime.h>

// FFD cubic B-spline flow generation, separable, contraction order x -> y -> z.
// mesh: [4][3][23][27][23] f32, out: [4][3][160][192][160] f32, spacing 8 all axes.
// d = (i&7)/8 (8 distinct weight rows shared by all axes), pivot = i>>3.
//
// Stage C writes full 128B lines per store instruction: 8 lanes per output row,
// lane zt covers z = 32k + 4*zt .. +3  (q = 4k + (zt>>1), W rows 4*(zt&1)..+3).

#define SPX 160
#define SPY 192
#define SPZ 160
#define CPX 23
#define CPY 27
#define CPZ 23
#define CZP 25   // padded LDS row stride (odd, coprime with 32 banks)

__global__ __launch_bounds__(256, 8) void ffd_kernel(const float* __restrict__ mesh,
                                                     float* __restrict__ out) {
    const int yb  = blockIdx.x;   // 0..23  (y blocks of 8)
    const int xb  = blockIdx.y;   // 0..19  (x blocks of 8)
    const int bc  = blockIdx.z;   // 0..11  (b*3 + c)
    const int tid = threadIdx.x;

    __shared__ __align__(16) float wlds[8][4];
    __shared__ float tX[8][4][CZP];    // x-contracted:   [x8][b2][cz]
    __shared__ float tXY[8][8][CZP];   // x+y-contracted: [x8][y8][cz]

    // cubic B-spline weight table for the 8 fractional offsets
    if (tid < 32) {
        int j = tid >> 2, a = tid & 3;
        float d  = (float)j * 0.125f;
        float d2 = d * d, d3 = d2 * d;
        float w;
        if (a == 0)      { float e = 1.0f - d; w = e * e * e * (1.0f / 6.0f); }
        else if (a == 1) { w = 0.5f * d3 - d2 + (2.0f / 3.0f); }
        else if (a == 2) { w = -0.5f * d3 + 0.5f * d2 + 0.5f * d + (1.0f / 6.0f); }
        else             { w = d3 * (1.0f / 6.0f); }
        wlds[j][a] = w;
    }
    __syncthreads();

    // stage A: contract x directly from global (mesh is L2-resident).
    // tX[x8][b2][cz] = sum_a wlds[x8][a] * mesh[bc][xb+a][yb+b2][cz]
    const float* mch = mesh + (size_t)bc * (CPX * CPY * CPZ);
    for (int i = tid; i < 8 * 4 * CPZ; i += 256) {   // 736 outputs
        int cz = i % CPZ;
        int r  = i / CPZ;
        int b2 = r & 3;
        int x8 = r >> 2;
        const float* mp = mch + (size_t)xb * (CPY * CPZ) + (yb + b2) * CPZ + cz;
        float acc = wlds[x8][0] * mp[0]
                  + wlds[x8][1] * mp[CPY * CPZ]
                  + wlds[x8][2] * mp[2 * CPY * CPZ]
                  + wlds[x8][3] * mp[3 * CPY * CPZ];
        tX[x8][b2][cz] = acc;
    }
    __syncthreads();

    // stage B: contract y.
    // tXY[x8][y8][cz] = sum_b2 wlds[y8][b2] * tX[x8][b2][cz]
    for (int i = tid; i < 8 * 8 * CPZ; i += 256) {   // 1472 outputs
        int cz = i % CPZ;
        int r  = i / CPZ;
        int y8 = r & 7;
        int x8 = r >> 3;
        float acc = wlds[y8][0] * tX[x8][0][cz]
                  + wlds[y8][1] * tX[x8][1][cz]
                  + wlds[y8][2] * tX[x8][2][cz]
                  + wlds[y8][3] * tX[x8][3][cz];
        tXY[x8][y8][cz] = acc;
    }
    __syncthreads();

    // stage C: expand z and store. 8 lanes per (x8,y8) row, 2 rows per thread.
    // out z = 32k + 4*zt + j  ->  q = 4k + (zt>>1), e = 4*(zt&1) + j.
    const int zt = tid & 7;        // lane within row-group
    const int h  = zt & 1;         // which half of the weight table
    const int qo = zt >> 1;        // q offset within the chunk

    // W rows 4h..4h+3 (broadcast float4 reads from LDS)
    const float4 Wr0 = *(const float4*)&wlds[4 * h + 0][0];
    const float4 Wr1 = *(const float4*)&wlds[4 * h + 1][0];
    const float4 Wr2 = *(const float4*)&wlds[4 * h + 2][0];
    const float4 Wr3 = *(const float4*)&wlds[4 * h + 3][0];

    float* oblk = out + ((size_t)bc * SPX * SPY
                       + (size_t)(xb * 8) * SPY
                       + (size_t)(yb * 8)) * SPZ;
    #pragma unroll
    for (int pass = 0; pass < 2; ++pass) {
        int row = pass * 32 + (tid >> 3);   // 0..63
        int x8 = row >> 3, y8 = row & 7;
        const float* trow = &tXY[x8][y8][0];
        float* orow = oblk + ((size_t)x8 * SPY + (size_t)y8) * SPZ;
        #pragma unroll
        for (int k = 0; k < 5; ++k) {
            int qa = 4 * k + qo;
            float m0 = trow[qa];
            float m1 = trow[qa + 1];
            float m2 = trow[qa + 2];
            float m3 = trow[qa + 3];
            float4 o;
            o.x = Wr0.x * m0 + Wr0.y * m1 + Wr0.z * m2 + Wr0.w * m3;
            o.y = Wr1.x * m0 + Wr1.y * m1 + Wr1.z * m2 + Wr1.w * m3;
            o.z = Wr2.x * m0 + Wr2.y * m1 + Wr2.z * m2 + Wr2.w * m3;
            o.w = Wr3.x * m0 + Wr3.y * m1 + Wr3.z * m2 + Wr3.w * m3;
            *(float4*)&orow[32 * k + 4 * zt] = o;
        }
    }
}

extern "C" void kernel_launch(void* const* d_in, const int* in_sizes, int n_in,
                              void* d_out, int out_size, void* d_ws, size_t ws_size,
                              hipStream_t stream) {
    const float* mesh = (const float*)d_in[0];
    float* out = (float*)d_out;
    dim3 grid(SPY / 8, SPX / 8, 4 * 3);   // (24, 20, 12)
    ffd_kernel<<<grid, 256, 0, stream>>>(mesh, out);
}